// Round 14
// baseline (1037.649 us; speedup 1.0000x reference)
//
#include <hip/hip_runtime.h>
#include <stdint.h>

#define N_NODES   100000
#define N_EDGES   800000
#define NODE_DIM  128
#define HIDDEN    256
#define OUT_DIM   512
#define N_LAYERS  4
#define N_GRAPHS  64
#define POOL_CHUNKS 8
#define SCAN_BLK  1024
#define SCAN_NB   ((N_NODES + SCAN_BLK - 1) / SCAN_BLK)   // 98

typedef _Float16 f16;
typedef __attribute__((ext_vector_type(8))) _Float16 f16x8;
typedef __attribute__((ext_vector_type(4))) _Float16 f16x4;
typedef __attribute__((ext_vector_type(4))) float    f32x4;

// ---------------- fp32 -> fp16 conversion (vectorized) ----------------
__global__ void k_f2h(const float* __restrict__ in, f16* __restrict__ out, int n4) {
    int i = blockIdx.x * 256 + threadIdx.x;
    if (i < n4) {
        f32x4 v = *(const f32x4*)(in + (size_t)i * 4);
        f16x4 o;
        o[0] = (f16)v[0]; o[1] = (f16)v[1]; o[2] = (f16)v[2]; o[3] = (f16)v[3];
        *(f16x4*)(out + (size_t)i * 4) = o;
    }
}

// ---------------- CSR build: histogram over dst ----------------
__global__ void k_hist(const int* __restrict__ ei, int* __restrict__ deg) {
    int e = blockIdx.x * 256 + threadIdx.x;
    if (e < N_EDGES) atomicAdd(&deg[ei[N_EDGES + e]], 1);
}

// ---------------- CSR build: 3-phase device-wide exclusive scan ----------------
__global__ __launch_bounds__(1024) void k_scan1(const int* __restrict__ deg,
                                                int* __restrict__ rowptr,
                                                int* __restrict__ bsums) {
    __shared__ int tmp[SCAN_BLK];
    int tid = threadIdx.x;
    int i = blockIdx.x * SCAN_BLK + tid;
    int v = (i < N_NODES) ? deg[i] : 0;
    tmp[tid] = v;
    __syncthreads();
    for (int off = 1; off < SCAN_BLK; off <<= 1) {
        int t = (tid >= off) ? tmp[tid - off] : 0;
        __syncthreads();
        tmp[tid] += t;
        __syncthreads();
    }
    if (i < N_NODES) rowptr[i] = tmp[tid] - v;        // local exclusive prefix
    if (tid == SCAN_BLK - 1) bsums[blockIdx.x] = tmp[tid];
}

__global__ __launch_bounds__(128) void k_scan2(const int* __restrict__ bsums,
                                               int* __restrict__ boffs,
                                               int* __restrict__ rowptr) {
    __shared__ int tmp[128];
    int tid = threadIdx.x;
    int v = (tid < SCAN_NB) ? bsums[tid] : 0;
    tmp[tid] = v;
    __syncthreads();
    for (int off = 1; off < 128; off <<= 1) {
        int t = (tid >= off) ? tmp[tid - off] : 0;
        __syncthreads();
        tmp[tid] += t;
        __syncthreads();
    }
    if (tid < SCAN_NB) boffs[tid] = tmp[tid] - v;     // exclusive block offset
    if (tid == 127) rowptr[N_NODES] = tmp[127];       // total = N_EDGES
}

__global__ __launch_bounds__(1024) void k_scan3(int* __restrict__ rowptr,
                                                const int* __restrict__ boffs,
                                                int* __restrict__ cursor) {
    int i = blockIdx.x * SCAN_BLK + threadIdx.x;
    if (i < N_NODES) {
        int r = rowptr[i] + boffs[blockIdx.x];
        rowptr[i] = r;
        cursor[i] = r;
    }
}

// ---------------- CSR build: scatter src into col ----------------
__global__ void k_scatter(const int* __restrict__ ei, int* __restrict__ cursor,
                          int* __restrict__ col) {
    int e = blockIdx.x * 256 + threadIdx.x;
    if (e < N_EDGES) {
        int d = ei[N_EDGES + e];
        int p = atomicAdd(&cursor[d], 1);
        col[p] = ei[e];
    }
}

// ---------------- aggregation: z = (1+eps)*h + sum_{s in N(v)} h[s], fp16 out ----------------
// 4-deep software-pipelined gather (round-11 verified: 96.5 -> 69 us).
__global__ __launch_bounds__(256) void k_agg(const f16* __restrict__ h,
                                             const int* __restrict__ rowptr,
                                             const int* __restrict__ col,
                                             const float* __restrict__ eps, int layer,
                                             f16* __restrict__ z) {
    int node = blockIdx.x * 4 + (threadIdx.x >> 6);
    if (node >= N_NODES) return;
    int lane = threadIdx.x & 63;
    int c0 = lane * 4;                         // 64 lanes x 4 ch = 256
    float e1 = 1.0f + eps[layer];
    f16x4 hv = *(const f16x4*)(h + (size_t)node * HIDDEN + c0);
    float a0 = e1 * (float)hv[0], a1 = e1 * (float)hv[1];
    float a2 = e1 * (float)hv[2], a3 = e1 * (float)hv[3];
    int jb = rowptr[node], je = rowptr[node + 1];
    int j = jb;
    for (; j + 4 <= je; j += 4) {
        int s0 = col[j], s1 = col[j + 1], s2 = col[j + 2], s3 = col[j + 3];
        f16x4 v0 = *(const f16x4*)(h + (size_t)s0 * HIDDEN + c0);
        f16x4 v1 = *(const f16x4*)(h + (size_t)s1 * HIDDEN + c0);
        f16x4 v2 = *(const f16x4*)(h + (size_t)s2 * HIDDEN + c0);
        f16x4 v3 = *(const f16x4*)(h + (size_t)s3 * HIDDEN + c0);
        a0 += (float)v0[0] + (float)v1[0] + (float)v2[0] + (float)v3[0];
        a1 += (float)v0[1] + (float)v1[1] + (float)v2[1] + (float)v3[1];
        a2 += (float)v0[2] + (float)v1[2] + (float)v2[2] + (float)v3[2];
        a3 += (float)v0[3] + (float)v1[3] + (float)v2[3] + (float)v3[3];
    }
    for (; j < je; ++j) {
        int s = col[j];
        f16x4 v = *(const f16x4*)(h + (size_t)s * HIDDEN + c0);
        a0 += (float)v[0]; a1 += (float)v[1]; a2 += (float)v[2]; a3 += (float)v[3];
    }
    f16x4 o;
    o[0] = (f16)a0; o[1] = (f16)a1; o[2] = (f16)a2; o[3] = (f16)a3;
    *(f16x4*)(z + (size_t)node * HIDDEN + c0) = o;
}

// ---------------- B-resident GEMM v4: half-B LDS (64 KB) for 2 blocks/CU ----------------
// Grid (nx, 2): blockIdx.y picks the 128-col half of B staged in LDS (XOR-swizzled,
// one barrier). 512 threads, per-wave independent 16-row x 128-col slabs (straight
// load->compute loop; ping-pong removed, measured neutral). 2 blocks/CU -> 4 waves/SIMD
// doubles TLP to raise the GEMM's HBM duty cycle (was ~10 GB/s/CU of a 24.6 share).
// acc[8]+a[8] ~= 110 VGPR: no spill at __launch_bounds__(512).
template<int K>
__global__ __launch_bounds__(512) void k_gemm(const f16* __restrict__ A,
                                              const f16* __restrict__ B,
                                              const float* __restrict__ bias,
                                              f16* __restrict__ C, int nsl16) {
    constexpr int NPANEL = K >> 6;           // 2 (K=128) or 4 (K=256)
    constexpr int NKS    = K >> 5;           // 4 or 8 K-steps of 32
    __shared__ f16 Bs[NPANEL * 128 * 64];    // 32 or 64 KB (half of out-cols)
    const int tid = threadIdx.x, wid = tid >> 6, lane = tid & 63;
    const int hy  = blockIdx.y;              // column half 0/1
    const int klo = lane >> 4;               // k-group 0..3
    const int l15 = lane & 15;

    // ---- stage this half of B once (swizzled via pre-swizzled global source) ----
#pragma unroll
    for (int p = 0; p < NPANEL; ++p) {
#pragma unroll
        for (int r = 0; r < 2; ++r) {
            int chunk = (r << 9) + tid;                  // 0..1023 within panel
            int brow = chunk >> 3, c8 = chunk & 7;
            int sc8  = c8 ^ (brow & 7);
            const f16* src = B + (size_t)((hy << 7) + brow) * K + (p << 6) + sc8 * 8;
            f16* dst = Bs + (p << 13) + (size_t)((r << 9) + (wid << 6)) * 8;
            __builtin_amdgcn_global_load_lds((const __attribute__((address_space(1))) void*)src,
                                             (__attribute__((address_space(3))) void*)dst, 16, 0, 0);
        }
    }
    __syncthreads();   // ONLY barrier in the kernel

    // ---- per-wave independent 16-row slabs ----
    for (int s = blockIdx.x * 8 + wid; s < nsl16; s += (gridDim.x << 3)) {
        const int r0 = s << 4;
        f16x8 a[NKS];
        const f16* arow = A + (size_t)(r0 + l15) * K + (klo << 3);
#pragma unroll
        for (int ks = 0; ks < NKS; ++ks)
            a[ks] = *(const f16x8*)(arow + (ks << 5));
        f32x4 acc[8] = {};
#pragma unroll
        for (int ks = 0; ks < NKS; ++ks) {
            const int kk = ((ks & 1) << 2) | klo;
            const f16* pb = Bs + ((ks >> 1) << 13);
#pragma unroll
            for (int n = 0; n < 8; ++n) {
                int rb = (n << 4) + l15;
                f16x8 bf = *(const f16x8*)(pb + rb * 64 + ((kk ^ (rb & 7)) << 3));
                acc[n] = __builtin_amdgcn_mfma_f32_16x16x32_f16(a[ks], bf, acc[n], 0, 0, 0);
            }
        }
        // epilogue: bias + relu + fp16 store. D: col=lane&15, row=(lane>>4)*4+j
#pragma unroll
        for (int n = 0; n < 8; ++n) {
            int gc = (hy << 7) + (n << 4) + l15;
            float bv = bias[gc];
#pragma unroll
            for (int j = 0; j < 4; ++j) {
                int gr = r0 + (klo << 2) + j;
                float v = fmaxf(acc[n][j] + bv, 0.0f);
                C[(size_t)gr * HIDDEN + gc] = (f16)v;
            }
        }
    }
}

// ---------------- segment starts from sorted batch (atomic-free) ----------------
__global__ void k_bounds(const int* __restrict__ batch, int* __restrict__ starts) {
    int i = blockIdx.x * 256 + threadIdx.x;
    if (i >= N_NODES) return;
    int g  = batch[i];
    int gp = (i == 0) ? -1 : batch[i - 1];
    for (int q = gp + 1; q <= g; ++q) starts[q] = i;
    if (i == N_NODES - 1) {
        for (int q = g + 1; q <= N_GRAPHS; ++q) starts[q] = N_NODES;
    }
}

// ---------------- pooled partial sums (atomic-free; batch sorted & contiguous) ----------------
__global__ __launch_bounds__(256) void k_pool(const f16* __restrict__ h,
                                              const int* __restrict__ starts,
                                              float* __restrict__ part) {
    int g = blockIdx.x, ch = blockIdx.y, c = threadIdx.x;
    int s = starts[g], e = starts[g + 1];
    int len = e - s;
    int per = (len + POOL_CHUNKS - 1) / POOL_CHUNKS;
    int lo = s + ch * per;
    int hi = lo + per; if (hi > e) hi = e;
    float acc = 0.0f;
    for (int n = lo; n < hi; ++n) acc += (float)h[(size_t)n * HIDDEN + c];
    part[((size_t)g * POOL_CHUNKS + ch) * HIDDEN + c] = acc;
}

// ---------------- head MLP (fp32, tiny) ----------------
__global__ __launch_bounds__(256) void k_head(const float* __restrict__ part,
                                              const int* __restrict__ starts,
                                              const float* __restrict__ w1,
                                              const float* __restrict__ b1,
                                              const float* __restrict__ w2,
                                              const float* __restrict__ b2,
                                              float* __restrict__ out) {
    __shared__ float hg[HIDDEN];
    __shared__ float t[HIDDEN];
    int g = blockIdx.x, tid = threadIdx.x;
    int cnti = starts[g + 1] - starts[g];
    float cnt = (float)(cnti > 1 ? cnti : 1);
    float s = 0.0f;
#pragma unroll
    for (int ch = 0; ch < POOL_CHUNKS; ++ch)
        s += part[((size_t)g * POOL_CHUNKS + ch) * HIDDEN + tid];
    hg[tid] = s / cnt;
    __syncthreads();
    float a = b1[tid];
    for (int k = 0; k < HIDDEN; ++k) a += hg[k] * w1[(size_t)tid * HIDDEN + k];
    t[tid] = fmaxf(a, 0.0f);
    __syncthreads();
    for (int j = tid; j < OUT_DIM; j += 256) {
        float o = b2[j];
        for (int k = 0; k < HIDDEN; ++k) o += t[k] * w2[(size_t)j * HIDDEN + k];
        out[(size_t)g * OUT_DIM + j] = o;
    }
}

extern "C" void kernel_launch(void* const* d_in, const int* in_sizes, int n_in,
                              void* d_out, int out_size, void* d_ws, size_t ws_size,
                              hipStream_t stream) {
    const float* x      = (const float*)d_in[0];
    const int*   ei     = (const int*)d_in[1];
    const int*   batch  = (const int*)d_in[2];
    const float* node_w = (const float*)d_in[3];
    const float* node_b = (const float*)d_in[4];
    const float* gw1    = (const float*)d_in[5];
    const float* gb1    = (const float*)d_in[6];
    const float* gw2    = (const float*)d_in[7];
    const float* gb2    = (const float*)d_in[8];
    const float* eps    = (const float*)d_in[9];
    const float* ow1    = (const float*)d_in[10];
    const float* ob1    = (const float*)d_in[11];
    const float* ow2    = (const float*)d_in[12];
    const float* ob2    = (const float*)d_in[13];
    float* out = (float*)d_out;

    // ---- workspace layout ----
    char* p = (char*)d_ws;
    auto alloc = [&](size_t bytes) {
        char* r = p;
        p += (bytes + 255) & ~(size_t)255;
        return (void*)r;
    };
    f16* hb   = (f16*)alloc((size_t)N_NODES * HIDDEN * 2);
    f16* zb   = (f16*)alloc((size_t)N_NODES * HIDDEN * 2);
    f16* tb   = (f16*)alloc((size_t)N_NODES * HIDDEN * 2);
    f16* xb   = (f16*)alloc((size_t)N_NODES * NODE_DIM * 2);
    f16* nwb  = (f16*)alloc((size_t)HIDDEN * NODE_DIM * 2);
    f16* w1b  = (f16*)alloc((size_t)N_LAYERS * HIDDEN * HIDDEN * 2);
    f16* w2b  = (f16*)alloc((size_t)N_LAYERS * HIDDEN * HIDDEN * 2);
    int* deg    = (int*)alloc((size_t)N_NODES * 4);
    int* rowptr = (int*)alloc((size_t)(N_NODES + 1) * 4);
    int* cursor = (int*)alloc((size_t)N_NODES * 4);
    int* col    = (int*)alloc((size_t)N_EDGES * 4);
    float* part = (float*)alloc((size_t)N_GRAPHS * POOL_CHUNKS * HIDDEN * 4);
    int* starts = (int*)alloc((size_t)(N_GRAPHS + 1) * 4);
    int* bsums  = (int*)alloc((size_t)SCAN_NB * 4);
    int* boffs  = (int*)alloc((size_t)SCAN_NB * 4);
    (void)in_sizes; (void)n_in; (void)out_size; (void)ws_size;

    // ---- zero what we accumulate into ----
    hipMemsetAsync(deg, 0, (size_t)N_NODES * 4, stream);

    // ---- fp16 conversions ----
    k_f2h<<<(N_NODES * NODE_DIM / 4 + 255) / 256, 256, 0, stream>>>(x, xb, N_NODES * NODE_DIM / 4);
    k_f2h<<<(HIDDEN * NODE_DIM / 4 + 255) / 256, 256, 0, stream>>>(node_w, nwb, HIDDEN * NODE_DIM / 4);
    k_f2h<<<(N_LAYERS * HIDDEN * HIDDEN / 4 + 255) / 256, 256, 0, stream>>>(gw1, w1b, N_LAYERS * HIDDEN * HIDDEN / 4);
    k_f2h<<<(N_LAYERS * HIDDEN * HIDDEN / 4 + 255) / 256, 256, 0, stream>>>(gw2, w2b, N_LAYERS * HIDDEN * HIDDEN / 4);

    // ---- CSR build ----
    k_hist<<<(N_EDGES + 255) / 256, 256, 0, stream>>>(ei, deg);
    k_scan1<<<SCAN_NB, SCAN_BLK, 0, stream>>>(deg, rowptr, bsums);
    k_scan2<<<1, 128, 0, stream>>>(bsums, boffs, rowptr);
    k_scan3<<<SCAN_NB, SCAN_BLK, 0, stream>>>(rowptr, boffs, cursor);
    k_scatter<<<(N_EDGES + 255) / 256, 256, 0, stream>>>(ei, cursor, col);

    // ---- segment bounds ----
    k_bounds<<<(N_NODES + 255) / 256, 256, 0, stream>>>(batch, starts);

    // ---- node projection ----
    const int NSL16 = N_NODES / 16;            // 6250 (exact)
    dim3 ggrid(256, 2);
    k_gemm<NODE_DIM><<<ggrid, 512, 0, stream>>>(xb, nwb, node_b, hb, NSL16);

    // ---- GIN layers ----
    for (int l = 0; l < N_LAYERS; ++l) {
        k_agg<<<(N_NODES + 3) / 4, 256, 0, stream>>>(hb, rowptr, col, eps, l, zb);
        k_gemm<HIDDEN><<<ggrid, 512, 0, stream>>>(zb, w1b + (size_t)l * HIDDEN * HIDDEN,
                                                  gb1 + (size_t)l * HIDDEN, tb, NSL16);
        k_gemm<HIDDEN><<<ggrid, 512, 0, stream>>>(tb, w2b + (size_t)l * HIDDEN * HIDDEN,
                                                  gb2 + (size_t)l * HIDDEN, hb, NSL16);
    }

    // ---- pooling + head ----
    dim3 pgrid(N_GRAPHS, POOL_CHUNKS);
    k_pool<<<pgrid, 256, 0, stream>>>(hb, starts, part);
    k_head<<<N_GRAPHS, 256, 0, stream>>>(part, starts, ow1, ob1, ow2, ob2, out);
}

// Round 15
// 694.985 us; speedup vs baseline: 1.4931x; 1.4931x over previous
//
#include <hip/hip_runtime.h>
#include <stdint.h>

#define N_NODES   100000
#define N_EDGES   800000
#define NODE_DIM  128
#define HIDDEN    256
#define OUT_DIM   512
#define N_LAYERS  4
#define N_GRAPHS  64
#define POOL_CHUNKS 8
#define SCAN_BLK  1024
#define SCAN_NB   ((N_NODES + SCAN_BLK - 1) / SCAN_BLK)   // 98

typedef _Float16 f16;
typedef __attribute__((ext_vector_type(8))) _Float16 f16x8;
typedef __attribute__((ext_vector_type(4))) _Float16 f16x4;
typedef __attribute__((ext_vector_type(4))) float    f32x4;

// ---------------- fp32 -> fp16 conversion (vectorized) ----------------
__global__ void k_f2h(const float* __restrict__ in, f16* __restrict__ out, int n4) {
    int i = blockIdx.x * 256 + threadIdx.x;
    if (i < n4) {
        f32x4 v = *(const f32x4*)(in + (size_t)i * 4);
        f16x4 o;
        o[0] = (f16)v[0]; o[1] = (f16)v[1]; o[2] = (f16)v[2]; o[3] = (f16)v[3];
        *(f16x4*)(out + (size_t)i * 4) = o;
    }
}

// ---------------- CSR build: histogram over dst ----------------
__global__ void k_hist(const int* __restrict__ ei, int* __restrict__ deg) {
    int e = blockIdx.x * 256 + threadIdx.x;
    if (e < N_EDGES) atomicAdd(&deg[ei[N_EDGES + e]], 1);
}

// ---------------- CSR build: 3-phase device-wide exclusive scan ----------------
__global__ __launch_bounds__(1024) void k_scan1(const int* __restrict__ deg,
                                                int* __restrict__ rowptr,
                                                int* __restrict__ bsums) {
    __shared__ int tmp[SCAN_BLK];
    int tid = threadIdx.x;
    int i = blockIdx.x * SCAN_BLK + tid;
    int v = (i < N_NODES) ? deg[i] : 0;
    tmp[tid] = v;
    __syncthreads();
    for (int off = 1; off < SCAN_BLK; off <<= 1) {
        int t = (tid >= off) ? tmp[tid - off] : 0;
        __syncthreads();
        tmp[tid] += t;
        __syncthreads();
    }
    if (i < N_NODES) rowptr[i] = tmp[tid] - v;        // local exclusive prefix
    if (tid == SCAN_BLK - 1) bsums[blockIdx.x] = tmp[tid];
}

__global__ __launch_bounds__(128) void k_scan2(const int* __restrict__ bsums,
                                               int* __restrict__ boffs,
                                               int* __restrict__ rowptr) {
    __shared__ int tmp[128];
    int tid = threadIdx.x;
    int v = (tid < SCAN_NB) ? bsums[tid] : 0;
    tmp[tid] = v;
    __syncthreads();
    for (int off = 1; off < 128; off <<= 1) {
        int t = (tid >= off) ? tmp[tid - off] : 0;
        __syncthreads();
        tmp[tid] += t;
        __syncthreads();
    }
    if (tid < SCAN_NB) boffs[tid] = tmp[tid] - v;     // exclusive block offset
    if (tid == 127) rowptr[N_NODES] = tmp[127];       // total = N_EDGES
}

__global__ __launch_bounds__(1024) void k_scan3(int* __restrict__ rowptr,
                                                const int* __restrict__ boffs,
                                                int* __restrict__ cursor) {
    int i = blockIdx.x * SCAN_BLK + threadIdx.x;
    if (i < N_NODES) {
        int r = rowptr[i] + boffs[blockIdx.x];
        rowptr[i] = r;
        cursor[i] = r;
    }
}

// ---------------- CSR build: scatter src into col ----------------
__global__ void k_scatter(const int* __restrict__ ei, int* __restrict__ cursor,
                          int* __restrict__ col) {
    int e = blockIdx.x * 256 + threadIdx.x;
    if (e < N_EDGES) {
        int d = ei[N_EDGES + e];
        int p = atomicAdd(&cursor[d], 1);
        col[p] = ei[e];
    }
}

// ---------------- aggregation v2: half-wave paired gather ----------------
// Lane loads f16x8 (16B): lanes 0-31 cover neighbor j's 512B row, lanes 32-63 cover
// neighbor j+1 -> one issue slot per 2 neighbors, 8 neighbors in flight at 4-deep
// unroll (vs 4 before). Final __shfl_xor(32) merges the two half-accumulators.
__global__ __launch_bounds__(256) void k_agg(const f16* __restrict__ h,
                                             const int* __restrict__ rowptr,
                                             const int* __restrict__ col,
                                             const float* __restrict__ eps, int layer,
                                             f16* __restrict__ z) {
    int node = blockIdx.x * 4 + (threadIdx.x >> 6);
    if (node >= N_NODES) return;
    int lane = threadIdx.x & 63;
    int half = lane >> 5;                      // 0: neighbor j, 1: neighbor j+1
    int c0 = (lane & 31) * 8;                  // 32 lanes x 8 ch = 256
    float e1 = 1.0f + eps[layer];
    float a0 = 0, a1 = 0, a2 = 0, a3 = 0, a4 = 0, a5 = 0, a6 = 0, a7 = 0;
    int jb = rowptr[node], je = rowptr[node + 1];
    int j = jb;
    for (; j + 8 <= je; j += 8) {
        int s0 = col[j     + half];
        int s1 = col[j + 2 + half];
        int s2 = col[j + 4 + half];
        int s3 = col[j + 6 + half];
        f16x8 v0 = *(const f16x8*)(h + (size_t)s0 * HIDDEN + c0);
        f16x8 v1 = *(const f16x8*)(h + (size_t)s1 * HIDDEN + c0);
        f16x8 v2 = *(const f16x8*)(h + (size_t)s2 * HIDDEN + c0);
        f16x8 v3 = *(const f16x8*)(h + (size_t)s3 * HIDDEN + c0);
        a0 += (float)v0[0] + (float)v1[0] + (float)v2[0] + (float)v3[0];
        a1 += (float)v0[1] + (float)v1[1] + (float)v2[1] + (float)v3[1];
        a2 += (float)v0[2] + (float)v1[2] + (float)v2[2] + (float)v3[2];
        a3 += (float)v0[3] + (float)v1[3] + (float)v2[3] + (float)v3[3];
        a4 += (float)v0[4] + (float)v1[4] + (float)v2[4] + (float)v3[4];
        a5 += (float)v0[5] + (float)v1[5] + (float)v2[5] + (float)v3[5];
        a6 += (float)v0[6] + (float)v1[6] + (float)v2[6] + (float)v3[6];
        a7 += (float)v0[7] + (float)v1[7] + (float)v2[7] + (float)v3[7];
    }
    for (; j + 2 <= je; j += 2) {
        int s = col[j + half];
        f16x8 v = *(const f16x8*)(h + (size_t)s * HIDDEN + c0);
        a0 += (float)v[0]; a1 += (float)v[1]; a2 += (float)v[2]; a3 += (float)v[3];
        a4 += (float)v[4]; a5 += (float)v[5]; a6 += (float)v[6]; a7 += (float)v[7];
    }
    if (j < je && half == 0) {                 // odd last neighbor
        int s = col[j];
        f16x8 v = *(const f16x8*)(h + (size_t)s * HIDDEN + c0);
        a0 += (float)v[0]; a1 += (float)v[1]; a2 += (float)v[2]; a3 += (float)v[3];
        a4 += (float)v[4]; a5 += (float)v[5]; a6 += (float)v[6]; a7 += (float)v[7];
    }
    if (half == 0) {                           // self term once
        f16x8 hv = *(const f16x8*)(h + (size_t)node * HIDDEN + c0);
        a0 += e1 * (float)hv[0]; a1 += e1 * (float)hv[1];
        a2 += e1 * (float)hv[2]; a3 += e1 * (float)hv[3];
        a4 += e1 * (float)hv[4]; a5 += e1 * (float)hv[5];
        a6 += e1 * (float)hv[6]; a7 += e1 * (float)hv[7];
    }
    a0 += __shfl_xor(a0, 32); a1 += __shfl_xor(a1, 32);
    a2 += __shfl_xor(a2, 32); a3 += __shfl_xor(a3, 32);
    a4 += __shfl_xor(a4, 32); a5 += __shfl_xor(a5, 32);
    a6 += __shfl_xor(a6, 32); a7 += __shfl_xor(a7, 32);
    if (half == 0) {
        f16x8 o;
        o[0] = (f16)a0; o[1] = (f16)a1; o[2] = (f16)a2; o[3] = (f16)a3;
        o[4] = (f16)a4; o[5] = (f16)a5; o[6] = (f16)a6; o[7] = (f16)a7;
        *(f16x8*)(z + (size_t)node * HIDDEN + c0) = o;
    }
}

// ---------------- B-resident GEMM v3 (round-13 verified ~38us): 512 threads, ----------------
// per-wave 16-row slabs, ping-pong A-prefetch, B entirely in LDS (one barrier).
template<int K>
__global__ __launch_bounds__(512) void k_gemm(const f16* __restrict__ A,
                                              const f16* __restrict__ B,
                                              const float* __restrict__ bias,
                                              f16* __restrict__ C, int nsl16) {
    constexpr int NPANEL = K >> 6;           // 2 (K=128) or 4 (K=256)
    constexpr int NKS    = K >> 5;           // 4 or 8 K-steps of 32
    __shared__ f16 Bs[NPANEL * 256 * 64];    // 64 or 128 KB
    const int tid = threadIdx.x, wid = tid >> 6, lane = tid & 63;
    const int klo = lane >> 4;               // k-group 0..3
    const int l15 = lane & 15;

    // ---- stage all of B once (swizzled via pre-swizzled global source) ----
#pragma unroll
    for (int p = 0; p < NPANEL; ++p) {
#pragma unroll
        for (int r = 0; r < 4; ++r) {
            int chunk = (r << 9) + tid;                  // 0..2047 within panel
            int brow = chunk >> 3, c8 = chunk & 7;
            int sc8  = c8 ^ (brow & 7);
            const f16* src = B + (size_t)brow * K + (p << 6) + sc8 * 8;
            f16* dst = Bs + (p << 14) + (size_t)((r << 9) + (wid << 6)) * 8;
            __builtin_amdgcn_global_load_lds((const __attribute__((address_space(1))) void*)src,
                                             (__attribute__((address_space(3))) void*)dst, 16, 0, 0);
        }
    }
    __syncthreads();   // ONLY barrier in the kernel

    auto loada = [&](f16x8 (&a)[NKS], int slab) {
        const f16* arow = A + (size_t)((slab << 4) + l15) * K + (klo << 3);
#pragma unroll
        for (int ks = 0; ks < NKS; ++ks)
            a[ks] = *(const f16x8*)(arow + (ks << 5));
    };
    auto compute = [&](const f16x8 (&a)[NKS], int slab) {
        f32x4 acc[16] = {};
#pragma unroll
        for (int ks = 0; ks < NKS; ++ks) {
            const int kk = ((ks & 1) << 2) | klo;
            const f16* pb = Bs + ((ks >> 1) << 14);
#pragma unroll
            for (int n = 0; n < 16; ++n) {
                int rb = (n << 4) + l15;
                f16x8 bf = *(const f16x8*)(pb + rb * 64 + ((kk ^ (rb & 7)) << 3));
                acc[n] = __builtin_amdgcn_mfma_f32_16x16x32_f16(a[ks], bf, acc[n], 0, 0, 0);
            }
        }
#pragma unroll
        for (int n = 0; n < 16; ++n) {
            int gc = (n << 4) + l15;
            float bv = bias[gc];
#pragma unroll
            for (int j = 0; j < 4; ++j) {
                int gr = (slab << 4) + (klo << 2) + j;
                float v = fmaxf(acc[n][j] + bv, 0.0f);
                C[(size_t)gr * HIDDEN + gc] = (f16)v;
            }
        }
    };

    // ---- per-wave ping-pong pipelined slab loop (static reg names, no dyn index) ----
    const int STRIDE = gridDim.x * 8;
    int s = blockIdx.x * 8 + wid;
    if (s >= nsl16) return;
    f16x8 aA[NKS], aB[NKS];
    loada(aA, s);
    for (;;) {
        int s2 = s + STRIDE;
        if (s2 < nsl16) loada(aB, s2);      // issue loads BEFORE compute -> overlap
        compute(aA, s);
        if (s2 >= nsl16) break;
        int s3 = s2 + STRIDE;
        if (s3 < nsl16) loada(aA, s3);
        compute(aB, s2);
        if (s3 >= nsl16) break;
        s = s3;
    }
}

// ---------------- segment starts from sorted batch (atomic-free) ----------------
__global__ void k_bounds(const int* __restrict__ batch, int* __restrict__ starts) {
    int i = blockIdx.x * 256 + threadIdx.x;
    if (i >= N_NODES) return;
    int g  = batch[i];
    int gp = (i == 0) ? -1 : batch[i - 1];
    for (int q = gp + 1; q <= g; ++q) starts[q] = i;
    if (i == N_NODES - 1) {
        for (int q = g + 1; q <= N_GRAPHS; ++q) starts[q] = N_NODES;
    }
}

// ---------------- pooled partial sums (atomic-free; batch sorted & contiguous) ----------------
__global__ __launch_bounds__(256) void k_pool(const f16* __restrict__ h,
                                              const int* __restrict__ starts,
                                              float* __restrict__ part) {
    int g = blockIdx.x, ch = blockIdx.y, c = threadIdx.x;
    int s = starts[g], e = starts[g + 1];
    int len = e - s;
    int per = (len + POOL_CHUNKS - 1) / POOL_CHUNKS;
    int lo = s + ch * per;
    int hi = lo + per; if (hi > e) hi = e;
    float acc = 0.0f;
    for (int n = lo; n < hi; ++n) acc += (float)h[(size_t)n * HIDDEN + c];
    part[((size_t)g * POOL_CHUNKS + ch) * HIDDEN + c] = acc;
}

// ---------------- head MLP (fp32, tiny) ----------------
__global__ __launch_bounds__(256) void k_head(const float* __restrict__ part,
                                              const int* __restrict__ starts,
                                              const float* __restrict__ w1,
                                              const float* __restrict__ b1,
                                              const float* __restrict__ w2,
                                              const float* __restrict__ b2,
                                              float* __restrict__ out) {
    __shared__ float hg[HIDDEN];
    __shared__ float t[HIDDEN];
    int g = blockIdx.x, tid = threadIdx.x;
    int cnti = starts[g + 1] - starts[g];
    float cnt = (float)(cnti > 1 ? cnti : 1);
    float s = 0.0f;
#pragma unroll
    for (int ch = 0; ch < POOL_CHUNKS; ++ch)
        s += part[((size_t)g * POOL_CHUNKS + ch) * HIDDEN + tid];
    hg[tid] = s / cnt;
    __syncthreads();
    float a = b1[tid];
    for (int k = 0; k < HIDDEN; ++k) a += hg[k] * w1[(size_t)tid * HIDDEN + k];
    t[tid] = fmaxf(a, 0.0f);
    __syncthreads();
    for (int j = tid; j < OUT_DIM; j += 256) {
        float o = b2[j];
        for (int k = 0; k < HIDDEN; ++k) o += t[k] * w2[(size_t)j * HIDDEN + k];
        out[(size_t)g * OUT_DIM + j] = o;
    }
}

extern "C" void kernel_launch(void* const* d_in, const int* in_sizes, int n_in,
                              void* d_out, int out_size, void* d_ws, size_t ws_size,
                              hipStream_t stream) {
    const float* x      = (const float*)d_in[0];
    const int*   ei     = (const int*)d_in[1];
    const int*   batch  = (const int*)d_in[2];
    const float* node_w = (const float*)d_in[3];
    const float* node_b = (const float*)d_in[4];
    const float* gw1    = (const float*)d_in[5];
    const float* gb1    = (const float*)d_in[6];
    const float* gw2    = (const float*)d_in[7];
    const float* gb2    = (const float*)d_in[8];
    const float* eps    = (const float*)d_in[9];
    const float* ow1    = (const float*)d_in[10];
    const float* ob1    = (const float*)d_in[11];
    const float* ow2    = (const float*)d_in[12];
    const float* ob2    = (const float*)d_in[13];
    float* out = (float*)d_out;

    // ---- workspace layout ----
    char* p = (char*)d_ws;
    auto alloc = [&](size_t bytes) {
        char* r = p;
        p += (bytes + 255) & ~(size_t)255;
        return (void*)r;
    };
    f16* hb   = (f16*)alloc((size_t)N_NODES * HIDDEN * 2);
    f16* zb   = (f16*)alloc((size_t)N_NODES * HIDDEN * 2);
    f16* tb   = (f16*)alloc((size_t)N_NODES * HIDDEN * 2);
    f16* xb   = (f16*)alloc((size_t)N_NODES * NODE_DIM * 2);
    f16* nwb  = (f16*)alloc((size_t)HIDDEN * NODE_DIM * 2);
    f16* w1b  = (f16*)alloc((size_t)N_LAYERS * HIDDEN * HIDDEN * 2);
    f16* w2b  = (f16*)alloc((size_t)N_LAYERS * HIDDEN * HIDDEN * 2);
    int* deg    = (int*)alloc((size_t)N_NODES * 4);
    int* rowptr = (int*)alloc((size_t)(N_NODES + 1) * 4);
    int* cursor = (int*)alloc((size_t)N_NODES * 4);
    int* col    = (int*)alloc((size_t)N_EDGES * 4);
    float* part = (float*)alloc((size_t)N_GRAPHS * POOL_CHUNKS * HIDDEN * 4);
    int* starts = (int*)alloc((size_t)(N_GRAPHS + 1) * 4);
    int* bsums  = (int*)alloc((size_t)SCAN_NB * 4);
    int* boffs  = (int*)alloc((size_t)SCAN_NB * 4);
    (void)in_sizes; (void)n_in; (void)out_size; (void)ws_size;

    // ---- zero what we accumulate into ----
    hipMemsetAsync(deg, 0, (size_t)N_NODES * 4, stream);

    // ---- fp16 conversions ----
    k_f2h<<<(N_NODES * NODE_DIM / 4 + 255) / 256, 256, 0, stream>>>(x, xb, N_NODES * NODE_DIM / 4);
    k_f2h<<<(HIDDEN * NODE_DIM / 4 + 255) / 256, 256, 0, stream>>>(node_w, nwb, HIDDEN * NODE_DIM / 4);
    k_f2h<<<(N_LAYERS * HIDDEN * HIDDEN / 4 + 255) / 256, 256, 0, stream>>>(gw1, w1b, N_LAYERS * HIDDEN * HIDDEN / 4);
    k_f2h<<<(N_LAYERS * HIDDEN * HIDDEN / 4 + 255) / 256, 256, 0, stream>>>(gw2, w2b, N_LAYERS * HIDDEN * HIDDEN / 4);

    // ---- CSR build ----
    k_hist<<<(N_EDGES + 255) / 256, 256, 0, stream>>>(ei, deg);
    k_scan1<<<SCAN_NB, SCAN_BLK, 0, stream>>>(deg, rowptr, bsums);
    k_scan2<<<1, 128, 0, stream>>>(bsums, boffs, rowptr);
    k_scan3<<<SCAN_NB, SCAN_BLK, 0, stream>>>(rowptr, boffs, cursor);
    k_scatter<<<(N_EDGES + 255) / 256, 256, 0, stream>>>(ei, cursor, col);

    // ---- segment bounds ----
    k_bounds<<<(N_NODES + 255) / 256, 256, 0, stream>>>(batch, starts);

    // ---- node projection ----
    const int NSL16 = N_NODES / 16;            // 6250 (exact)
    k_gemm<NODE_DIM><<<256, 512, 0, stream>>>(xb, nwb, node_b, hb, NSL16);

    // ---- GIN layers ----
    for (int l = 0; l < N_LAYERS; ++l) {
        k_agg<<<(N_NODES + 3) / 4, 256, 0, stream>>>(hb, rowptr, col, eps, l, zb);
        k_gemm<HIDDEN><<<256, 512, 0, stream>>>(zb, w1b + (size_t)l * HIDDEN * HIDDEN,
                                                gb1 + (size_t)l * HIDDEN, tb, NSL16);
        k_gemm<HIDDEN><<<256, 512, 0, stream>>>(tb, w2b + (size_t)l * HIDDEN * HIDDEN,
                                                gb2 + (size_t)l * HIDDEN, hb, NSL16);
    }

    // ---- pooling + head ----
    dim3 pgrid(N_GRAPHS, POOL_CHUNKS);
    k_pool<<<pgrid, 256, 0, stream>>>(hb, starts, part);
    k_head<<<N_GRAPHS, 256, 0, stream>>>(part, starts, ow1, ob1, ow2, ob2, out);
}